// Round 10
// baseline (1670.905 us; speedup 1.0000x reference)
//
#include <hip/hip_runtime.h>
#include <hip/hip_bf16.h>
#include <math.h>

#define NTOK 1024
#define DDIM 768
#define MDIM 3072
#define GN 4
#define EN 8
#define NEXP 32
#define NPAIR 8192
#define EPSW 1e-6f
#define MAXRB 96   // max row-blocks: 31 partial + 8192/128 full

typedef __attribute__((ext_vector_type(4))) float f32x4;
typedef __attribute__((ext_vector_type(4))) int   i32x4;
typedef __attribute__((ext_vector_type(4))) unsigned short u16x4;
typedef __attribute__((ext_vector_type(8))) __bf16 bf16x8;

__device__ __forceinline__ unsigned short f2bf(float f) {
  unsigned u = __builtin_bit_cast(unsigned, f);
  u += 0x7FFFu + ((u >> 16) & 1u);
  return (unsigned short)(u >> 16);
}

// ---------------------------------------------------------------------------
// Init + zero-y + x->bf16.
// ---------------------------------------------------------------------------
__global__ void init_kernel(int* __restrict__ p) { p[threadIdx.x] = 0; }

__global__ __launch_bounds__(256) void zero_y(float* __restrict__ y) {
  ((f32x4*)y)[blockIdx.x * 256 + threadIdx.x] = (f32x4){0.f, 0.f, 0.f, 0.f};
}

__global__ __launch_bounds__(256) void x2bf(const float* __restrict__ x,
                                            unsigned short* __restrict__ xb) {
  const int i = (blockIdx.x * 256 + threadIdx.x) * 16;
#pragma unroll
  for (int j = 0; j < 4; ++j) {
    const f32x4 v = *(const f32x4*)(x + i + j * 4);
    u16x4 p = { f2bf(v.x), f2bf(v.y), f2bf(v.z), f2bf(v.w) };
    *(u16x4*)(xb + i + j * 4) = p;
  }
}

// ---------------------------------------------------------------------------
// Kernel 1: gating (proven correct).
// ---------------------------------------------------------------------------
__global__ __launch_bounds__(256) void gating_kernel(
    const float* __restrict__ x, const float* __restrict__ Wg,
    const float* __restrict__ bg, const float* __restrict__ We,
    const float* __restrict__ be, int* __restrict__ counts,
    int* __restrict__ pair_e, float* __restrict__ pair_w)
{
  __shared__ float xr[DDIM];
  __shared__ float logits[36];
  const int n = blockIdx.x;
  const int tid = threadIdx.x;
  const float* xp = x + (size_t)n * DDIM;
  for (int d = tid; d < DDIM; d += 256) xr[d] = xp[d];
  __syncthreads();

  const int w = tid >> 6, lane = tid & 63;
  for (int j = 0; j < 9; ++j) {
    const int o = w + 4 * j;  // 0..35
    float s = 0.f;
    if (o < 4) {
      for (int d = lane; d < DDIM; d += 64) s += xr[d] * Wg[d * GN + o];
    } else {
      const int g = (o - 4) >> 3, e = (o - 4) & 7;
      const float* wp = We + (size_t)g * DDIM * EN + e;
      for (int d = lane; d < DDIM; d += 64) s += xr[d] * wp[d * EN];
    }
    for (int off = 32; off; off >>= 1) s += __shfl_xor(s, off);
    if (lane == 0) logits[o] = s + ((o < 4) ? bg[o] : be[o - 4]);
  }
  __syncthreads();

  if (tid == 0) {
    float gl[4];
    for (int i = 0; i < 4; ++i) gl[i] = logits[i];
    int i0 = 0;
    for (int i = 1; i < 4; ++i) if (gl[i] > gl[i0]) i0 = i;
    int i1 = -1;
    for (int i = 0; i < 4; ++i) {
      if (i == i0) continue;
      if (i1 < 0 || gl[i] > gl[i1]) i1 = i;
    }
    const float m = gl[i0];
    const float e1 = expf(gl[i1] - m);
    const float s2 = 1.f + e1;
    float gv[2] = { 1.f / s2, e1 / s2 };
    int gi[2] = { i0, i1 };
    for (int r = 0; r < 2; ++r) if (gv[r] < EPSW) gv[r] = 0.f;

    for (int r = 0; r < 2; ++r) {
      const int g = gi[r];
      float el[8];
      for (int e = 0; e < 8; ++e) el[e] = logits[4 + g * 8 + e];
      int sel[4];
      for (int q = 0; q < 4; ++q) {
        int best = -1;
        for (int e = 0; e < 8; ++e) {
          bool used = false;
          for (int p = 0; p < q; ++p) if (sel[p] == e) used = true;
          if (used) continue;
          if (best < 0 || el[e] > el[best]) best = e;
        }
        sel[q] = best;
      }
      const float mm = el[sel[0]];
      float ex[4]; float ss = 0.f;
      for (int q = 0; q < 4; ++q) { ex[q] = expf(el[sel[q]] - mm); ss += ex[q]; }
      for (int q = 0; q < 4; ++q) {
        float ew = ex[q] / ss;
        if (ew < EPSW) ew = 0.f;
        const int gbl = g * 8 + sel[q];
        const int j = r * 4 + q;
        pair_e[n * 8 + j] = gbl;
        pair_w[n * 8 + j] = gv[r] * ew;
        atomicAdd(&counts[gbl], 1);
      }
    }
  }
}

// ---------------------------------------------------------------------------
// Kernel 2: scan + row-block lookup table (rb -> expert, local by).
// ---------------------------------------------------------------------------
__global__ void scan_kernel(const int* __restrict__ counts, int* __restrict__ offsets,
                            int* __restrict__ rb_ge, int* __restrict__ rb_by,
                            int* __restrict__ nrb)
{
  if (threadIdx.x == 0) {
    int a = 0, n = 0;
    for (int e = 0; e < NEXP; ++e) {
      offsets[e] = a;
      const int c = counts[e];
      a += c;
      for (int b = 0; b * 128 < c; ++b) { rb_ge[n] = e; rb_by[n] = b; ++n; }
    }
    *nrb = n;
  }
}

// ---------------------------------------------------------------------------
// Kernel 3: slot bookkeeping (FC1 gathers token rows directly from xb).
// ---------------------------------------------------------------------------
__global__ __launch_bounds__(256) void scatter_kernel(
    const int* __restrict__ pair_e, const float* __restrict__ pair_w,
    const int* __restrict__ offsets, int* __restrict__ cursor,
    int* __restrict__ slot_tok, float* __restrict__ slot_w)
{
  const int idx = blockIdx.x * 256 + threadIdx.x;
  if (idx < NPAIR) {
    const int e = pair_e[idx];
    const int s = offsets[e] + atomicAdd(&cursor[e], 1);
    slot_tok[s] = idx >> 3;
    slot_w[s] = pair_w[idx];
  }
}

// ---------------------------------------------------------------------------
// Kernel 4: flat-grid fused GEMM, fp32 weights direct (no repack).
// blockIdx.x = row-block (via rb table), .y = n-block, .z = K-chunk (FC2).
// BM=128, BN=128, BK=32, 4 waves, mfma 16x16x32 bf16. 3-deep register
// pipeline, period-6 unrolled, ONE barrier per K-step; all vmcnt waits
// compiler-inserted (round-7 lesson). K-split (KS>1) partials accumulate
// via the atomic epilogue; bias added by chunk 0 only.
// GATHER=1: A rows = xb[slot_tok[slot]] (FC1).  GATHER=0: A rows = H (FC2).
// EPI 0: H = bf16(gelu(C + b1)).  EPI 1: atomicAdd y[tok] += slot_w*(C+b2).
// ---------------------------------------------------------------------------
template<int K, int NLD, int EPI, int GATHER, int KS>
__global__ __launch_bounds__(256, 4) void moe_gemm_fl(
    const unsigned short* __restrict__ Abase, const float* __restrict__ W,
    const float* __restrict__ bias, const int* __restrict__ counts,
    const int* __restrict__ offsets, const float* __restrict__ slot_w,
    const int* __restrict__ slot_tok, const int* __restrict__ rb_ge,
    const int* __restrict__ rb_by, const int* __restrict__ nrb,
    unsigned short* __restrict__ Hout, float* __restrict__ Yout)
{
  constexpr int KC = K / KS;      // K-chunk
  constexpr int NT = KC / 32;     // K-steps: 24 for both GEMMs; %6==0
  constexpr int BUFB = 16384;     // one LDS buffer: A 8KB + B 8KB

  const int rb = blockIdx.x;
  if (rb >= *nrb) return;
  const int ge = rb_ge[rb];
  const int by = rb_by[rb];
  const int cnt = counts[ge];
  const int off = offsets[ge];
  const int nb = blockIdx.y;
  const int ks = (KS > 1) ? blockIdx.z : 0;
  const int kbase = ks * KC;
  const int tid = threadIdx.x;

  __shared__ __align__(16) unsigned char lds[2 * BUFB];

  // ---- A staging geometry: thread covers rows am, am+64; 16B chunk ac.
  const int am = tid >> 2, ac = tid & 3;
  const int asw0 = am * 64 + ((ac ^ ((am ^ (am >> 2)) & 3)) * 16);
  const int asw1 = asw0 + 4096;

  // ---- B staging geometry: thread = (kq, ln); 16 dwords per K-step.
  const int kq = tid >> 5, ln = tid & 31;
  const float* bp = W + (size_t)ge * K * NLD + (size_t)(kbase + kq * 4) * NLD
                      + nb * 128 + ln;
  int bwr[4];
#pragma unroll
  for (int ii = 0; ii < 4; ++ii) {
    const int n = ln + 32 * ii;
    const int s = (n ^ (n >> 2)) & 3;
    bwr[ii] = 8192 + n * 64 + (((kq >> 1) ^ s) * 16) + ((kq & 1) * 8);
  }

  // ---- fragment geometry
  const int w = tid >> 6, lane = tid & 63;
  const int wr = (w >> 1) * 64, wc = (w & 1) * 64;
  const int l15 = lane & 15, l4 = lane >> 4;
  int aoff[4], boff[4];
#pragma unroll
  for (int mf = 0; mf < 4; ++mf) {
    const int m = wr + mf * 16 + l15;
    aoff[mf] = m * 64 + ((l4 ^ ((m ^ (m >> 2)) & 3)) * 16);
  }
#pragma unroll
  for (int nf = 0; nf < 4; ++nf) {
    const int n = wc + nf * 16 + l15;
    boff[nf] = 8192 + n * 64 + ((l4 ^ ((n ^ (n >> 2)) & 3)) * 16);
  }

  // ---- A row pointers
  int gr0 = by * 128 + am;      if (gr0 >= cnt) gr0 = cnt - 1;
  int gr1 = by * 128 + am + 64; if (gr1 >= cnt) gr1 = cnt - 1;
  const unsigned short* ap0;
  const unsigned short* ap1;
  if (GATHER) {
    ap0 = Abase + (size_t)slot_tok[off + gr0] * K + kbase + ac * 8;
    ap1 = Abase + (size_t)slot_tok[off + gr1] * K + kbase + ac * 8;
  } else {
    ap0 = Abase + (size_t)(off + gr0) * K + kbase + ac * 8;
    ap1 = Abase + (size_t)(off + gr1) * K + kbase + ac * 8;
  }

  f32x4 acc[4][4];
#pragma unroll
  for (int mf = 0; mf < 4; ++mf)
#pragma unroll
    for (int nf = 0; nf < 4; ++nf)
      acc[mf][nf] = (f32x4){0.f, 0.f, 0.f, 0.f};

  i32x4 aA0, aA1, aB0, aB1, aC0, aC1;
  float bA[16], bB[16], bC[16];

#define LOADA(T, R0, R1) { \
    R0 = *(const i32x4*)(ap0 + (T) * 32); \
    R1 = *(const i32x4*)(ap1 + (T) * 32); }
#define LOADB(T, BS) { _Pragma("unroll") \
    for (int ii = 0; ii < 4; ++ii) { _Pragma("unroll") \
      for (int jj = 0; jj < 4; ++jj) \
        BS[ii * 4 + jj] = bp[(size_t)((T) * 32 + jj) * NLD + 32 * ii]; } }
#define CVTW(R0, R1, BS, BASE) { \
    *(i32x4*)((BASE) + asw0) = R0; \
    *(i32x4*)((BASE) + asw1) = R1; \
    _Pragma("unroll") \
    for (int ii = 0; ii < 4; ++ii) { \
      u16x4 p = { f2bf(BS[ii*4+0]), f2bf(BS[ii*4+1]), f2bf(BS[ii*4+2]), f2bf(BS[ii*4+3]) }; \
      *(u16x4*)((BASE) + bwr[ii]) = p; } }
#define COMPUTE(BASE) { bf16x8 afr[4], bfr[4]; _Pragma("unroll") \
    for (int mf = 0; mf < 4; ++mf) \
      afr[mf] = __builtin_bit_cast(bf16x8, *(const i32x4*)((BASE) + aoff[mf])); \
    _Pragma("unroll") \
    for (int nf = 0; nf < 4; ++nf) \
      bfr[nf] = __builtin_bit_cast(bf16x8, *(const i32x4*)((BASE) + boff[nf])); \
    _Pragma("unroll") \
    for (int mf = 0; mf < 4; ++mf) { _Pragma("unroll") \
      for (int nf = 0; nf < 4; ++nf) \
        acc[mf][nf] = __builtin_amdgcn_mfma_f32_16x16x32_bf16( \
            afr[mf], bfr[nf], acc[mf][nf], 0, 0, 0); } }
#define STEP(T, C0, C1, CB, I0, I1, IB, BASE) { \
    if ((T) + 2 < NT) { LOADA((T) + 2, I0, I1); LOADB((T) + 2, IB); } \
    CVTW(C0, C1, CB, BASE); \
    asm volatile("s_waitcnt lgkmcnt(0)" ::: "memory"); \
    __builtin_amdgcn_s_barrier(); \
    COMPUTE(BASE); \
  }

  // ---- prologue: load tiles 0 (set A) and 1 (set B)
  LOADA(0, aA0, aA1); LOADB(0, bA);
  LOADA(1, aB0, aB1); LOADB(1, bB);

  for (int t = 0; t < NT; t += 6) {
    STEP(t + 0, aA0, aA1, bA, aC0, aC1, bC, lds);
    STEP(t + 1, aB0, aB1, bB, aA0, aA1, bA, lds + BUFB);
    STEP(t + 2, aC0, aC1, bC, aB0, aB1, bB, lds);
    STEP(t + 3, aA0, aA1, bA, aC0, aC1, bC, lds + BUFB);
    STEP(t + 4, aB0, aB1, bB, aA0, aA1, bA, lds);
    STEP(t + 5, aC0, aC1, bC, aB0, aB1, bB, lds + BUFB);
  }
#undef LOADA
#undef LOADB
#undef CVTW
#undef COMPUTE
#undef STEP

  // ---- epilogue. C/D layout: col = lane&15, row = (lane>>4)*4 + j
#pragma unroll
  for (int mf = 0; mf < 4; ++mf) {
    const int rb2 = by * 128 + wr + mf * 16 + l4 * 4;
    if constexpr (EPI == 0) {
#pragma unroll
      for (int nf = 0; nf < 4; ++nf) {
        const int col = nb * 128 + wc + nf * 16 + l15;
        const float bv = bias[(size_t)ge * NLD + col];
#pragma unroll
        for (int j = 0; j < 4; ++j) {
          const int r = rb2 + j;
          if (r < cnt) {
            const float v = acc[mf][nf][j] + bv;
            const float gl = 0.5f * v * (1.f + erff(v * 0.70710678118654752f));
            Hout[(size_t)(off + r) * NLD + col] = f2bf(gl);
          }
        }
      }
    } else {
#pragma unroll
      for (int j = 0; j < 4; ++j) {
        const int r = rb2 + j;
        if (r < cnt) {
          const int slot = off + r;
          const float sw = slot_w[slot];
          const int tok = slot_tok[slot];
#pragma unroll
          for (int nf = 0; nf < 4; ++nf) {
            const int col = nb * 128 + wc + nf * 16 + l15;
            const float bv = (ks == 0) ? bias[(size_t)ge * NLD + col] : 0.f;
            atomicAdd(&Yout[(size_t)tok * DDIM + col], sw * (acc[mf][nf][j] + bv));
          }
        }
      }
    }
  }
}

// ---------------------------------------------------------------------------
// Workspace layout (bytes):
//   0    counts[32]     128  offsets[32]    256  cursor[32]   384 nrb
//   512  rb_ge[96]      896  rb_by[96]
//   2048 pair_e[8192]   34816 pair_w[8192]
//   67584 slot_tok[8192] 100352 slot_w[8192]
//   135168 xb[1024][768] bf16 (1.57 MB)
//   12715008 H[8192][3072] bf16 (50.3 MB)    (ws ~1.2 GB available)
// ---------------------------------------------------------------------------
extern "C" void kernel_launch(void* const* d_in, const int* in_sizes, int n_in,
                              void* d_out, int out_size, void* d_ws, size_t ws_size,
                              hipStream_t stream)
{
  const float* x  = (const float*)d_in[0];
  const float* Wg = (const float*)d_in[1];
  const float* bg = (const float*)d_in[2];
  const float* We = (const float*)d_in[3];
  const float* be = (const float*)d_in[4];
  const float* W1 = (const float*)d_in[5];
  const float* b1 = (const float*)d_in[6];
  const float* W2 = (const float*)d_in[7];
  const float* b2 = (const float*)d_in[8];
  float* y = (float*)d_out;

  char* ws = (char*)d_ws;
  int*   counts   = (int*)(ws + 0);
  int*   offsets  = (int*)(ws + 128);
  int*   cursor   = (int*)(ws + 256);
  int*   nrb      = (int*)(ws + 384);
  int*   rb_ge    = (int*)(ws + 512);
  int*   rb_by    = (int*)(ws + 896);
  int*   pair_e   = (int*)(ws + 2048);
  float* pair_w   = (float*)(ws + 34816);
  int*   slot_tok = (int*)(ws + 67584);
  float* slot_w   = (float*)(ws + 100352);
  unsigned short* xb = (unsigned short*)(ws + 135168);
  unsigned short* H  = (unsigned short*)(ws + 12715008);

  init_kernel<<<1, 256, 0, stream>>>((int*)ws);
  zero_y<<<NTOK * DDIM / 1024, 256, 0, stream>>>(y);
  x2bf<<<NTOK * DDIM / 4096, 256, 0, stream>>>(x, xb);
  gating_kernel<<<NTOK, 256, 0, stream>>>(x, Wg, bg, We, be, counts, pair_e, pair_w);
  scan_kernel<<<1, 64, 0, stream>>>(counts, offsets, rb_ge, rb_by, nrb);
  scatter_kernel<<<NPAIR / 256, 256, 0, stream>>>(pair_e, pair_w, offsets, cursor,
                                                  slot_tok, slot_w);

  // FC1: flat grid (96 row-blocks x 24 n-blocks), W1 fp32 direct, A from xb.
  moe_gemm_fl<DDIM, MDIM, 0, 1, 1><<<dim3(MAXRB, MDIM / 128, 1), 256, 0, stream>>>(
      xb, W1, b1, counts, offsets, nullptr, slot_tok, rb_ge, rb_by, nrb, H, nullptr);
  // FC2: flat grid x K-split 4 (96 x 6 x 4), W2 fp32 direct, atomic into y.
  moe_gemm_fl<MDIM, DDIM, 1, 0, 4><<<dim3(MAXRB, DDIM / 128, 4), 256, 0, stream>>>(
      H, W2, b2, counts, offsets, slot_w, slot_tok, rb_ge, rb_by, nrb, nullptr, y);
}

// Round 11
// 560.288 us; speedup vs baseline: 2.9822x; 2.9822x over previous
//
#include <hip/hip_runtime.h>
#include <hip/hip_bf16.h>
#include <math.h>

#define NTOK 1024
#define DDIM 768
#define MDIM 3072
#define GN 4
#define EN 8
#define NEXP 32
#define NPAIR 8192
#define EPSW 1e-6f
#define MAXRB 96   // max row-blocks: 31 partial + 8192/128 full

typedef __attribute__((ext_vector_type(4))) float f32x4;
typedef __attribute__((ext_vector_type(4))) int   i32x4;
typedef __attribute__((ext_vector_type(4))) unsigned short u16x4;
typedef __attribute__((ext_vector_type(8))) __bf16 bf16x8;

__device__ __forceinline__ unsigned short f2bf(float f) {
  unsigned u = __builtin_bit_cast(unsigned, f);
  u += 0x7FFFu + ((u >> 16) & 1u);
  return (unsigned short)(u >> 16);
}

// ---------------------------------------------------------------------------
// Init + zero-y + x->bf16.
// ---------------------------------------------------------------------------
__global__ void init_kernel(int* __restrict__ p) { p[threadIdx.x] = 0; }

__global__ __launch_bounds__(256) void zero_y(float* __restrict__ y) {
  ((f32x4*)y)[blockIdx.x * 256 + threadIdx.x] = (f32x4){0.f, 0.f, 0.f, 0.f};
}

__global__ __launch_bounds__(256) void x2bf(const float* __restrict__ x,
                                            unsigned short* __restrict__ xb) {
  const int i = (blockIdx.x * 256 + threadIdx.x) * 16;
#pragma unroll
  for (int j = 0; j < 4; ++j) {
    const f32x4 v = *(const f32x4*)(x + i + j * 4);
    u16x4 p = { f2bf(v.x), f2bf(v.y), f2bf(v.z), f2bf(v.w) };
    *(u16x4*)(xb + i + j * 4) = p;
  }
}

// ---------------------------------------------------------------------------
// Kernel 1: gating (proven correct).
// ---------------------------------------------------------------------------
__global__ __launch_bounds__(256) void gating_kernel(
    const float* __restrict__ x, const float* __restrict__ Wg,
    const float* __restrict__ bg, const float* __restrict__ We,
    const float* __restrict__ be, int* __restrict__ counts,
    int* __restrict__ pair_e, float* __restrict__ pair_w)
{
  __shared__ float xr[DDIM];
  __shared__ float logits[36];
  const int n = blockIdx.x;
  const int tid = threadIdx.x;
  const float* xp = x + (size_t)n * DDIM;
  for (int d = tid; d < DDIM; d += 256) xr[d] = xp[d];
  __syncthreads();

  const int w = tid >> 6, lane = tid & 63;
  for (int j = 0; j < 9; ++j) {
    const int o = w + 4 * j;  // 0..35
    float s = 0.f;
    if (o < 4) {
      for (int d = lane; d < DDIM; d += 64) s += xr[d] * Wg[d * GN + o];
    } else {
      const int g = (o - 4) >> 3, e = (o - 4) & 7;
      const float* wp = We + (size_t)g * DDIM * EN + e;
      for (int d = lane; d < DDIM; d += 64) s += xr[d] * wp[d * EN];
    }
    for (int off = 32; off; off >>= 1) s += __shfl_xor(s, off);
    if (lane == 0) logits[o] = s + ((o < 4) ? bg[o] : be[o - 4]);
  }
  __syncthreads();

  if (tid == 0) {
    float gl[4];
    for (int i = 0; i < 4; ++i) gl[i] = logits[i];
    int i0 = 0;
    for (int i = 1; i < 4; ++i) if (gl[i] > gl[i0]) i0 = i;
    int i1 = -1;
    for (int i = 0; i < 4; ++i) {
      if (i == i0) continue;
      if (i1 < 0 || gl[i] > gl[i1]) i1 = i;
    }
    const float m = gl[i0];
    const float e1 = expf(gl[i1] - m);
    const float s2 = 1.f + e1;
    float gv[2] = { 1.f / s2, e1 / s2 };
    int gi[2] = { i0, i1 };
    for (int r = 0; r < 2; ++r) if (gv[r] < EPSW) gv[r] = 0.f;

    for (int r = 0; r < 2; ++r) {
      const int g = gi[r];
      float el[8];
      for (int e = 0; e < 8; ++e) el[e] = logits[4 + g * 8 + e];
      int sel[4];
      for (int q = 0; q < 4; ++q) {
        int best = -1;
        for (int e = 0; e < 8; ++e) {
          bool used = false;
          for (int p = 0; p < q; ++p) if (sel[p] == e) used = true;
          if (used) continue;
          if (best < 0 || el[e] > el[best]) best = e;
        }
        sel[q] = best;
      }
      const float mm = el[sel[0]];
      float ex[4]; float ss = 0.f;
      for (int q = 0; q < 4; ++q) { ex[q] = expf(el[sel[q]] - mm); ss += ex[q]; }
      for (int q = 0; q < 4; ++q) {
        float ew = ex[q] / ss;
        if (ew < EPSW) ew = 0.f;
        const int gbl = g * 8 + sel[q];
        const int j = r * 4 + q;
        pair_e[n * 8 + j] = gbl;
        pair_w[n * 8 + j] = gv[r] * ew;
        atomicAdd(&counts[gbl], 1);
      }
    }
  }
}

// ---------------------------------------------------------------------------
// Kernel 2: scan + row-block lookup table (rb -> expert, local by).
// ---------------------------------------------------------------------------
__global__ void scan_kernel(const int* __restrict__ counts, int* __restrict__ offsets,
                            int* __restrict__ rb_ge, int* __restrict__ rb_by,
                            int* __restrict__ nrb)
{
  if (threadIdx.x == 0) {
    int a = 0, n = 0;
    for (int e = 0; e < NEXP; ++e) {
      offsets[e] = a;
      const int c = counts[e];
      a += c;
      for (int b = 0; b * 128 < c; ++b) { rb_ge[n] = e; rb_by[n] = b; ++n; }
    }
    *nrb = n;
  }
}

// ---------------------------------------------------------------------------
// Kernel 3: slot bookkeeping (FC1 gathers token rows directly from xb).
// ---------------------------------------------------------------------------
__global__ __launch_bounds__(256) void scatter_kernel(
    const int* __restrict__ pair_e, const float* __restrict__ pair_w,
    const int* __restrict__ offsets, int* __restrict__ cursor,
    int* __restrict__ slot_tok, float* __restrict__ slot_w)
{
  const int idx = blockIdx.x * 256 + threadIdx.x;
  if (idx < NPAIR) {
    const int e = pair_e[idx];
    const int s = offsets[e] + atomicAdd(&cursor[e], 1);
    slot_tok[s] = idx >> 3;
    slot_w[s] = pair_w[idx];
  }
}

// ---------------------------------------------------------------------------
// Kernel 4: flat-grid fused GEMM, fp32 weights direct (no repack).
// blockIdx.x = row-block (via rb table), .y = n-block, .z = K-chunk (FC2).
// BM=128, BN=128, BK=32, 4 waves, mfma 16x16x32 bf16. 3-deep register
// pipeline, period-6 unrolled, ONE barrier per K-step; all vmcnt waits
// compiler-inserted. launch_bounds (256,2): round-10's (256,4) forced
// VGPR=64 -> acc/stage spill to scratch (WRITE_SIZE 24MB -> 1.2GB). The
// proven budget is VGPR~120, no spill.
// GATHER=1: A rows = xb[slot_tok[slot]] (FC1).  GATHER=0: A rows = H (FC2).
// EPI 0: H = bf16(gelu(C + b1)).  EPI 1: atomicAdd y[tok] += slot_w*(C+b2).
// ---------------------------------------------------------------------------
template<int K, int NLD, int EPI, int GATHER, int KS>
__global__ __launch_bounds__(256, 2) void moe_gemm_fl(
    const unsigned short* __restrict__ Abase, const float* __restrict__ W,
    const float* __restrict__ bias, const int* __restrict__ counts,
    const int* __restrict__ offsets, const float* __restrict__ slot_w,
    const int* __restrict__ slot_tok, const int* __restrict__ rb_ge,
    const int* __restrict__ rb_by, const int* __restrict__ nrb,
    unsigned short* __restrict__ Hout, float* __restrict__ Yout)
{
  constexpr int KC = K / KS;      // K-chunk
  constexpr int NT = KC / 32;     // K-steps: 24 for both GEMMs; %6==0
  constexpr int BUFB = 16384;     // one LDS buffer: A 8KB + B 8KB

  const int rb = blockIdx.x;
  if (rb >= *nrb) return;
  const int ge = rb_ge[rb];
  const int by = rb_by[rb];
  const int cnt = counts[ge];
  const int off = offsets[ge];
  const int nb = blockIdx.y;
  const int ks = (KS > 1) ? blockIdx.z : 0;
  const int kbase = ks * KC;
  const int tid = threadIdx.x;

  __shared__ __align__(16) unsigned char lds[2 * BUFB];

  // ---- A staging geometry: thread covers rows am, am+64; 16B chunk ac.
  const int am = tid >> 2, ac = tid & 3;
  const int asw0 = am * 64 + ((ac ^ ((am ^ (am >> 2)) & 3)) * 16);
  const int asw1 = asw0 + 4096;

  // ---- B staging geometry: thread = (kq, ln); 16 dwords per K-step.
  const int kq = tid >> 5, ln = tid & 31;
  const float* bp = W + (size_t)ge * K * NLD + (size_t)(kbase + kq * 4) * NLD
                      + nb * 128 + ln;
  int bwr[4];
#pragma unroll
  for (int ii = 0; ii < 4; ++ii) {
    const int n = ln + 32 * ii;
    const int s = (n ^ (n >> 2)) & 3;
    bwr[ii] = 8192 + n * 64 + (((kq >> 1) ^ s) * 16) + ((kq & 1) * 8);
  }

  // ---- fragment geometry
  const int w = tid >> 6, lane = tid & 63;
  const int wr = (w >> 1) * 64, wc = (w & 1) * 64;
  const int l15 = lane & 15, l4 = lane >> 4;
  int aoff[4], boff[4];
#pragma unroll
  for (int mf = 0; mf < 4; ++mf) {
    const int m = wr + mf * 16 + l15;
    aoff[mf] = m * 64 + ((l4 ^ ((m ^ (m >> 2)) & 3)) * 16);
  }
#pragma unroll
  for (int nf = 0; nf < 4; ++nf) {
    const int n = wc + nf * 16 + l15;
    boff[nf] = 8192 + n * 64 + ((l4 ^ ((n ^ (n >> 2)) & 3)) * 16);
  }

  // ---- A row pointers
  int gr0 = by * 128 + am;      if (gr0 >= cnt) gr0 = cnt - 1;
  int gr1 = by * 128 + am + 64; if (gr1 >= cnt) gr1 = cnt - 1;
  const unsigned short* ap0;
  const unsigned short* ap1;
  if (GATHER) {
    ap0 = Abase + (size_t)slot_tok[off + gr0] * K + kbase + ac * 8;
    ap1 = Abase + (size_t)slot_tok[off + gr1] * K + kbase + ac * 8;
  } else {
    ap0 = Abase + (size_t)(off + gr0) * K + kbase + ac * 8;
    ap1 = Abase + (size_t)(off + gr1) * K + kbase + ac * 8;
  }

  f32x4 acc[4][4];
#pragma unroll
  for (int mf = 0; mf < 4; ++mf)
#pragma unroll
    for (int nf = 0; nf < 4; ++nf)
      acc[mf][nf] = (f32x4){0.f, 0.f, 0.f, 0.f};

  i32x4 aA0, aA1, aB0, aB1, aC0, aC1;
  float bA[16], bB[16], bC[16];

#define LOADA(T, R0, R1) { \
    R0 = *(const i32x4*)(ap0 + (T) * 32); \
    R1 = *(const i32x4*)(ap1 + (T) * 32); }
#define LOADB(T, BS) { _Pragma("unroll") \
    for (int ii = 0; ii < 4; ++ii) { _Pragma("unroll") \
      for (int jj = 0; jj < 4; ++jj) \
        BS[ii * 4 + jj] = bp[(size_t)((T) * 32 + jj) * NLD + 32 * ii]; } }
#define CVTW(R0, R1, BS, BASE) { \
    *(i32x4*)((BASE) + asw0) = R0; \
    *(i32x4*)((BASE) + asw1) = R1; \
    _Pragma("unroll") \
    for (int ii = 0; ii < 4; ++ii) { \
      u16x4 p = { f2bf(BS[ii*4+0]), f2bf(BS[ii*4+1]), f2bf(BS[ii*4+2]), f2bf(BS[ii*4+3]) }; \
      *(u16x4*)((BASE) + bwr[ii]) = p; } }
#define COMPUTE(BASE) { bf16x8 afr[4], bfr[4]; _Pragma("unroll") \
    for (int mf = 0; mf < 4; ++mf) \
      afr[mf] = __builtin_bit_cast(bf16x8, *(const i32x4*)((BASE) + aoff[mf])); \
    _Pragma("unroll") \
    for (int nf = 0; nf < 4; ++nf) \
      bfr[nf] = __builtin_bit_cast(bf16x8, *(const i32x4*)((BASE) + boff[nf])); \
    _Pragma("unroll") \
    for (int mf = 0; mf < 4; ++mf) { _Pragma("unroll") \
      for (int nf = 0; nf < 4; ++nf) \
        acc[mf][nf] = __builtin_amdgcn_mfma_f32_16x16x32_bf16( \
            afr[mf], bfr[nf], acc[mf][nf], 0, 0, 0); } }
#define STEP(T, C0, C1, CB, I0, I1, IB, BASE) { \
    if ((T) + 2 < NT) { LOADA((T) + 2, I0, I1); LOADB((T) + 2, IB); } \
    CVTW(C0, C1, CB, BASE); \
    asm volatile("s_waitcnt lgkmcnt(0)" ::: "memory"); \
    __builtin_amdgcn_s_barrier(); \
    COMPUTE(BASE); \
  }

  // ---- prologue: load tiles 0 (set A) and 1 (set B)
  LOADA(0, aA0, aA1); LOADB(0, bA);
  LOADA(1, aB0, aB1); LOADB(1, bB);

  for (int t = 0; t < NT; t += 6) {
    STEP(t + 0, aA0, aA1, bA, aC0, aC1, bC, lds);
    STEP(t + 1, aB0, aB1, bB, aA0, aA1, bA, lds + BUFB);
    STEP(t + 2, aC0, aC1, bC, aB0, aB1, bB, lds);
    STEP(t + 3, aA0, aA1, bA, aC0, aC1, bC, lds + BUFB);
    STEP(t + 4, aB0, aB1, bB, aA0, aA1, bA, lds);
    STEP(t + 5, aC0, aC1, bC, aB0, aB1, bB, lds + BUFB);
  }
#undef LOADA
#undef LOADB
#undef CVTW
#undef COMPUTE
#undef STEP

  // ---- epilogue. C/D layout: col = lane&15, row = (lane>>4)*4 + j
#pragma unroll
  for (int mf = 0; mf < 4; ++mf) {
    const int rb2 = by * 128 + wr + mf * 16 + l4 * 4;
    if constexpr (EPI == 0) {
#pragma unroll
      for (int nf = 0; nf < 4; ++nf) {
        const int col = nb * 128 + wc + nf * 16 + l15;
        const float bv = bias[(size_t)ge * NLD + col];
#pragma unroll
        for (int j = 0; j < 4; ++j) {
          const int r = rb2 + j;
          if (r < cnt) {
            const float v = acc[mf][nf][j] + bv;
            const float gl = 0.5f * v * (1.f + erff(v * 0.70710678118654752f));
            Hout[(size_t)(off + r) * NLD + col] = f2bf(gl);
          }
        }
      }
    } else {
#pragma unroll
      for (int j = 0; j < 4; ++j) {
        const int r = rb2 + j;
        if (r < cnt) {
          const int slot = off + r;
          const float sw = slot_w[slot];
          const int tok = slot_tok[slot];
#pragma unroll
          for (int nf = 0; nf < 4; ++nf) {
            const int col = nb * 128 + wc + nf * 16 + l15;
            const float bv = (ks == 0) ? bias[(size_t)ge * NLD + col] : 0.f;
            atomicAdd(&Yout[(size_t)tok * DDIM + col], sw * (acc[mf][nf][j] + bv));
          }
        }
      }
    }
  }
}

// ---------------------------------------------------------------------------
// Workspace layout (bytes):
//   0    counts[32]     128  offsets[32]    256  cursor[32]   384 nrb
//   512  rb_ge[96]      896  rb_by[96]
//   2048 pair_e[8192]   34816 pair_w[8192]
//   67584 slot_tok[8192] 100352 slot_w[8192]
//   135168 xb[1024][768] bf16 (1.57 MB)
//   12715008 H[8192][3072] bf16 (50.3 MB)    (ws ~1.2 GB available)
// ---------------------------------------------------------------------------
extern "C" void kernel_launch(void* const* d_in, const int* in_sizes, int n_in,
                              void* d_out, int out_size, void* d_ws, size_t ws_size,
                              hipStream_t stream)
{
  const float* x  = (const float*)d_in[0];
  const float* Wg = (const float*)d_in[1];
  const float* bg = (const float*)d_in[2];
  const float* We = (const float*)d_in[3];
  const float* be = (const float*)d_in[4];
  const float* W1 = (const float*)d_in[5];
  const float* b1 = (const float*)d_in[6];
  const float* W2 = (const float*)d_in[7];
  const float* b2 = (const float*)d_in[8];
  float* y = (float*)d_out;

  char* ws = (char*)d_ws;
  int*   counts   = (int*)(ws + 0);
  int*   offsets  = (int*)(ws + 128);
  int*   cursor   = (int*)(ws + 256);
  int*   nrb      = (int*)(ws + 384);
  int*   rb_ge    = (int*)(ws + 512);
  int*   rb_by    = (int*)(ws + 896);
  int*   pair_e   = (int*)(ws + 2048);
  float* pair_w   = (float*)(ws + 34816);
  int*   slot_tok = (int*)(ws + 67584);
  float* slot_w   = (float*)(ws + 100352);
  unsigned short* xb = (unsigned short*)(ws + 135168);
  unsigned short* H  = (unsigned short*)(ws + 12715008);

  init_kernel<<<1, 256, 0, stream>>>((int*)ws);
  zero_y<<<NTOK * DDIM / 1024, 256, 0, stream>>>(y);
  x2bf<<<NTOK * DDIM / 4096, 256, 0, stream>>>(x, xb);
  gating_kernel<<<NTOK, 256, 0, stream>>>(x, Wg, bg, We, be, counts, pair_e, pair_w);
  scan_kernel<<<1, 64, 0, stream>>>(counts, offsets, rb_ge, rb_by, nrb);
  scatter_kernel<<<NPAIR / 256, 256, 0, stream>>>(pair_e, pair_w, offsets, cursor,
                                                  slot_tok, slot_w);

  // FC1: flat grid (96 row-blocks x 24 n-blocks), W1 fp32 direct, A from xb.
  moe_gemm_fl<DDIM, MDIM, 0, 1, 1><<<dim3(MAXRB, MDIM / 128, 1), 256, 0, stream>>>(
      xb, W1, b1, counts, offsets, nullptr, slot_tok, rb_ge, rb_by, nrb, H, nullptr);
  // FC2: flat grid x K-split 4 (96 x 6 x 4), W2 fp32 direct, atomic into y.
  moe_gemm_fl<MDIM, DDIM, 1, 0, 4><<<dim3(MAXRB, DDIM / 128, 4), 256, 0, stream>>>(
      H, W2, b2, counts, offsets, slot_w, slot_tok, rb_ge, rb_by, nrb, nullptr, y);
}